// Round 1
// baseline (155.128 us; speedup 1.0000x reference)
//
#include <hip/hip_runtime.h>

// Problem constants (from reference)
constexpr int N  = 20000;
constexpr int V  = 6;
constexpr int P  = 64;
constexpr int ND = 32;
constexpr float W_   = 1600.0f;
constexpr float H_   = 928.0f;
constexpr float EPS_ = 1e-5f;

// One wave (64 lanes) per (n,v) pair.
//   Phase 1: lanes 0..31 each compute projection for depth d=lane,
//            store xy_proj (float2, coalesced 256B) and mask (128B).
//   Phase 2: lane p owns ROI p (P==64==wave width). Depth coords are
//            broadcast via v_readlane (uniform -> SGPR), validity via
//            __ballot (SGPR pair); mask combining runs on scalar pipe.
__global__ __launch_bounds__(256) void box_corr(
    const float* __restrict__ points,   // N x 3  [img_id, x, y]
    const float* __restrict__ trans,    // V x V x 4 x 4
    const float* __restrict__ rois,     // V x P x 4  [x1,y1,x2,y2]
    float* __restrict__ out_xy,         // N x V x ND x 2
    float* __restrict__ out_mask,       // N x V x ND
    float* __restrict__ out_corr)       // N x V x P
{
    const int gwave = (int)((blockIdx.x * 256u + threadIdx.x) >> 6);
    const int lane  = (int)(threadIdx.x & 63u);
    if (gwave >= N * V) return;
    const int n = gwave / V;
    const int v = gwave - n * V;

    const float x   = points[n * 3 + 1];
    const float y   = points[n * 3 + 2];
    const int   img = (int)points[n * 3 + 0];

    float px = 0.0f, py = 0.0f;
    bool  ok = false;

    if (lane < ND) {
        // depths[k] = 0.5 + bin_size * k * (k+1), left-assoc f32 like jnp
        const float k   = (float)lane;
        const float bin = (float)(69.5 / 1056.0);  // f64 -> f32 once
        const float d   = __fadd_rn(0.5f, __fmul_rn(__fmul_rn(bin, k), __fadd_rn(k, 1.0f)));

        // pts_cam = [x*d, y*d, d, 1]
        const float p0 = __fmul_rn(x, d);
        const float p1 = __fmul_rn(y, d);

        const float* T = trans + ((size_t)v * V + img) * 16;
        // proj_i = ((T[i0]*p0 + T[i1]*p1) + T[i2]*d) + T[i3]   (no FMA contraction)
        const float r0 = __fadd_rn(__fadd_rn(__fadd_rn(__fmul_rn(T[0], p0), __fmul_rn(T[1], p1)), __fmul_rn(T[2], d)), T[3]);
        const float r1 = __fadd_rn(__fadd_rn(__fadd_rn(__fmul_rn(T[4], p0), __fmul_rn(T[5], p1)), __fmul_rn(T[6], d)), T[7]);
        const float r2 = __fadd_rn(__fadd_rn(__fadd_rn(__fmul_rn(T[8], p0), __fmul_rn(T[9], p1)), __fmul_rn(T[10], d)), T[11]);

        const float zc = fmaxf(r2, EPS_);
        px = r0 / zc;   // IEEE f32 divide (no fast-math)
        py = r1 / zc;
        ok = (r2 > EPS_) && (px >= 0.0f) && (px < W_) && (py >= 0.0f) && (py < H_);

        const size_t base = (size_t)gwave * ND + lane;
        ((float2*)out_xy)[base] = make_float2(px, py);
        out_mask[base] = ok ? 1.0f : 0.0f;
    }

    // validity bits for depths 0..31 (lanes >=32 contribute 0)
    const unsigned long long mbits = __ballot(ok);

    // lane p's ROI
    const float4 roi = ((const float4*)rois)[v * P + lane];

    bool hit = false;
    const int ipx = __float_as_int(px);
    const int ipy = __float_as_int(py);
    #pragma unroll
    for (int d = 0; d < ND; ++d) {
        const float xd = __int_as_float(__builtin_amdgcn_readlane(ipx, d));
        const float yd = __int_as_float(__builtin_amdgcn_readlane(ipy, d));
        const bool okd = (mbits >> d) & 1ull;
        hit = hit || (okd && (xd > roi.x) && (xd < roi.z) && (yd > roi.y) && (yd < roi.w));
    }

    out_corr[(size_t)gwave * P + lane] = hit ? 1.0f : 0.0f;
}

extern "C" void kernel_launch(void* const* d_in, const int* in_sizes, int n_in,
                              void* d_out, int out_size, void* d_ws, size_t ws_size,
                              hipStream_t stream) {
    const float* points = (const float*)d_in[0];   // 20000*3
    const float* trans  = (const float*)d_in[1];   // 6*6*4*4
    const float* rois   = (const float*)d_in[2];   // 6*64*4

    float* out      = (float*)d_out;
    float* out_xy   = out;                                   // 7,680,000
    float* out_mask = out + (size_t)N * V * ND * 2;          // 3,840,000
    float* out_corr = out_mask + (size_t)N * V * ND;         // 7,680,000

    const int waves  = N * V;            // 120000 waves, one per (n,v)
    const int blocks = (waves + 3) / 4;  // 4 waves / 256-thread block
    box_corr<<<blocks, 256, 0, stream>>>(points, trans, rois, out_xy, out_mask, out_corr);
}

// Round 2
// 123.547 us; speedup vs baseline: 1.2556x; 1.2556x over previous
//
#include <hip/hip_runtime.h>

constexpr int N  = 20000;
constexpr int V  = 6;
constexpr int P  = 64;
constexpr int ND = 32;
constexpr float W_   = 1600.0f;
constexpr float H_   = 928.0f;
constexpr float EPS_ = 1e-5f;

// One wave per TWO (n,v) pairs:
//   lanes 0..31  : depths 0..31 of pair A = 2*gw
//   lanes 32..63 : depths 0..31 of pair B = 2*gw+1
// Phase 1 is full-lane (projection + xy/mask stores, fully coalesced).
// Phase 2: lane p owns ROI p; iterate ONLY over valid depth bits
// (ctz loop on the ballot mask, uniform branch), broadcasting coords via
// readlane (dynamic uniform index) and accumulating hits as SGPR lane-masks.
__global__ __launch_bounds__(256) void box_corr(
    const float* __restrict__ points,   // N x 3  [img_id, x, y]
    const float* __restrict__ trans,    // V x V x 4 x 4
    const float* __restrict__ rois,     // V x P x 4  [x1,y1,x2,y2]
    float* __restrict__ out_xy,         // N x V x ND x 2
    float* __restrict__ out_mask,       // N x V x ND
    float* __restrict__ out_corr)       // N x V x P
{
    const int gw   = __builtin_amdgcn_readfirstlane(
                        (int)((blockIdx.x * 256u + threadIdx.x) >> 6));
    const int lane = (int)(threadIdx.x & 63u);
    if (gw >= (N * V) / 2) return;

    const int pA = 2 * gw;          // scalar
    const int pB = pA + 1;
    const int nA = pA / V, vA = pA - nA * V;
    const int nB = pB / V, vB = pB - nB * V;

    // Uniform point loads (scalar path), then per-half select.
    const float idA = points[nA * 3 + 0];
    const float xA  = points[nA * 3 + 1];
    const float yA  = points[nA * 3 + 2];
    const float idB = points[nB * 3 + 0];
    const float xB  = points[nB * 3 + 1];
    const float yB  = points[nB * 3 + 2];
    const int imgA = (int)idA;
    const int imgB = (int)idB;
    const int offA = (vA * V + imgA) * 16;   // floats
    const int offB = (vB * V + imgB) * 16;

    const bool hiHalf = lane >= 32;
    const int  dl     = lane & 31;
    const float x   = hiHalf ? xB : xA;
    const float y   = hiHalf ? yB : yA;
    const int   off = hiHalf ? offB : offA;

    // depths[k] = 0.5 + bin*k*(k+1), left-assoc f32 (matches jnp)
    const float k   = (float)dl;
    const float bin = (float)(69.5 / 1056.0);
    const float d   = __fadd_rn(0.5f, __fmul_rn(__fmul_rn(bin, k), __fadd_rn(k, 1.0f)));

    const float p0 = __fmul_rn(x, d);
    const float p1 = __fmul_rn(y, d);

    const float* T = trans + off;
    const float4 t0 = *(const float4*)(T + 0);
    const float4 t1 = *(const float4*)(T + 4);
    const float4 t2 = *(const float4*)(T + 8);
    // no FMA contraction: match numpy einsum's mul+add sequence
    const float r0 = __fadd_rn(__fadd_rn(__fadd_rn(__fmul_rn(t0.x, p0), __fmul_rn(t0.y, p1)), __fmul_rn(t0.z, d)), t0.w);
    const float r1 = __fadd_rn(__fadd_rn(__fadd_rn(__fmul_rn(t1.x, p0), __fmul_rn(t1.y, p1)), __fmul_rn(t1.z, d)), t1.w);
    const float r2 = __fadd_rn(__fadd_rn(__fadd_rn(__fmul_rn(t2.x, p0), __fmul_rn(t2.y, p1)), __fmul_rn(t2.z, d)), t2.w);

    const float zc = fmaxf(r2, EPS_);
    const float px = r0 / zc;   // IEEE divide — booleans must be exact
    const float py = r1 / zc;
    const bool  ok = (r2 > EPS_) && (px >= 0.0f) && (px < W_) && (py >= 0.0f) && (py < H_);

    // Full-wave coalesced stores: index gw*64 + lane is contiguous.
    const size_t base = (size_t)gw * 64 + lane;
    ((float2*)out_xy)[base] = make_float2(px, py);
    out_mask[base] = ok ? 1.0f : 0.0f;

    // Validity bits: low 32 = pair A depths, high 32 = pair B depths.
    const unsigned long long bal = __ballot(ok);
    unsigned long long mA = bal & 0xffffffffull;
    unsigned long long mB = bal >> 32;

    // lane p's ROI for each pair's view
    const float4 ra = ((const float4*)rois)[vA * P + lane];
    const float4 rb = ((const float4*)rois)[vB * P + lane];

    const int ipx = __float_as_int(px);
    const int ipy = __float_as_int(py);

    unsigned long long hA = 0, hB = 0;
    while (mA) {
        const int q = __builtin_ctzll(mA);   // uniform
        mA &= mA - 1;
        const float xd = __int_as_float(__builtin_amdgcn_readlane(ipx, q));
        const float yd = __int_as_float(__builtin_amdgcn_readlane(ipy, q));
        hA |= __ballot((xd > ra.x) && (xd < ra.z) && (yd > ra.y) && (yd < ra.w));
    }
    while (mB) {
        const int q = __builtin_ctzll(mB);   // uniform, lane = 32+q
        mB &= mB - 1;
        const float xd = __int_as_float(__builtin_amdgcn_readlane(ipx, q + 32));
        const float yd = __int_as_float(__builtin_amdgcn_readlane(ipy, q + 32));
        hB |= __ballot((xd > rb.x) && (xd < rb.z) && (yd > rb.y) && (yd < rb.w));
    }

    const float cA = ((hA >> lane) & 1ull) ? 1.0f : 0.0f;
    const float cB = ((hB >> lane) & 1ull) ? 1.0f : 0.0f;
    out_corr[(size_t)pA * P + lane] = cA;
    out_corr[(size_t)pB * P + lane] = cB;
}

extern "C" void kernel_launch(void* const* d_in, const int* in_sizes, int n_in,
                              void* d_out, int out_size, void* d_ws, size_t ws_size,
                              hipStream_t stream) {
    const float* points = (const float*)d_in[0];   // 20000*3
    const float* trans  = (const float*)d_in[1];   // 6*6*4*4
    const float* rois   = (const float*)d_in[2];   // 6*64*4

    float* out      = (float*)d_out;
    float* out_xy   = out;                                   // N*V*ND*2
    float* out_mask = out + (size_t)N * V * ND * 2;          // N*V*ND
    float* out_corr = out_mask + (size_t)N * V * ND;         // N*V*P

    const int waves  = (N * V) / 2;      // 60000 waves, 2 pairs each
    const int blocks = (waves + 3) / 4;  // 4 waves / 256-thread block
    box_corr<<<blocks, 256, 0, stream>>>(points, trans, rois, out_xy, out_mask, out_corr);
}

// Round 3
// 99.068 us; speedup vs baseline: 1.5659x; 1.2471x over previous
//
#include <hip/hip_runtime.h>
#include <math.h>

constexpr int N  = 20000;
constexpr int V  = 6;
constexpr int P  = 64;
constexpr int ND = 32;
constexpr float W_   = 1600.0f;
constexpr float H_   = 928.0f;
constexpr float EPS_ = 1e-5f;

// One wave per TWO (n,v) pairs (lanes 0..31 = pair A depths, 32..63 = pair B).
// Phase 1: full-lane projection + coalesced xy/mask stores (bit-identical to
//          the round-1/2 passing kernel).
// Phase 2: EXACT bbox prune. Valid projections cluster tightly (Mobius in d
//          with tiny constant terms), so per-ROI interval logic on the
//          [min,max] of valid points resolves hit/miss exactly for almost all
//          cells; only ROI-edge-straddling cells run a branchless unrolled
//          32-depth loop with +INF sentinels (invalid depths auto-fail).
__global__ __launch_bounds__(256) void box_corr(
    const float* __restrict__ points,   // N x 3  [img_id, x, y]
    const float* __restrict__ trans,    // V x V x 4 x 4
    const float* __restrict__ rois,     // V x P x 4  [x1,y1,x2,y2]
    float* __restrict__ out_xy,         // N x V x ND x 2
    float* __restrict__ out_mask,       // N x V x ND
    float* __restrict__ out_corr)       // N x V x P
{
    const int gw   = __builtin_amdgcn_readfirstlane(
                        (int)((blockIdx.x * 256u + threadIdx.x) >> 6));
    const int lane = (int)(threadIdx.x & 63u);
    if (gw >= (N * V) / 2) return;

    const int pA = 2 * gw;
    const int pB = pA + 1;
    const int nA = pA / V, vA = pA - nA * V;
    const int nB = pB / V, vB = pB - nB * V;

    const float idA = points[nA * 3 + 0];
    const float xA  = points[nA * 3 + 1];
    const float yA  = points[nA * 3 + 2];
    const float idB = points[nB * 3 + 0];
    const float xB  = points[nB * 3 + 1];
    const float yB  = points[nB * 3 + 2];
    const int imgA = (int)idA;
    const int imgB = (int)idB;
    const int offA = (vA * V + imgA) * 16;
    const int offB = (vB * V + imgB) * 16;

    const bool hiHalf = lane >= 32;
    const int  dl     = lane & 31;
    const float x   = hiHalf ? xB : xA;
    const float y   = hiHalf ? yB : yA;
    const int   off = hiHalf ? offB : offA;

    // depths[k] = 0.5 + bin*k*(k+1), left-assoc f32 (matches jnp)
    const float k   = (float)dl;
    const float bin = (float)(69.5 / 1056.0);
    const float d   = __fadd_rn(0.5f, __fmul_rn(__fmul_rn(bin, k), __fadd_rn(k, 1.0f)));

    const float p0 = __fmul_rn(x, d);
    const float p1 = __fmul_rn(y, d);

    const float* T = trans + off;
    const float4 t0 = *(const float4*)(T + 0);
    const float4 t1 = *(const float4*)(T + 4);
    const float4 t2 = *(const float4*)(T + 8);
    // no FMA contraction: match numpy einsum's mul+add sequence
    const float r0 = __fadd_rn(__fadd_rn(__fadd_rn(__fmul_rn(t0.x, p0), __fmul_rn(t0.y, p1)), __fmul_rn(t0.z, d)), t0.w);
    const float r1 = __fadd_rn(__fadd_rn(__fadd_rn(__fmul_rn(t1.x, p0), __fmul_rn(t1.y, p1)), __fmul_rn(t1.z, d)), t1.w);
    const float r2 = __fadd_rn(__fadd_rn(__fadd_rn(__fmul_rn(t2.x, p0), __fmul_rn(t2.y, p1)), __fmul_rn(t2.z, d)), t2.w);

    const float zc = fmaxf(r2, EPS_);
    const float px = r0 / zc;   // IEEE divide — booleans must be exact
    const float py = r1 / zc;
    const bool  ok = (r2 > EPS_) && (px >= 0.0f) && (px < W_) && (py >= 0.0f) && (py < H_);

    const size_t base = (size_t)gw * 64 + lane;
    ((float2*)out_xy)[base] = make_float2(px, py);
    out_mask[base] = ok ? 1.0f : 0.0f;

    const unsigned long long bal = __ballot(ok);

    float cA = 0.0f, cB = 0.0f;
    if (bal != 0ull) {
        const float4 ra = ((const float4*)rois)[vA * P + lane];
        const float4 rb = ((const float4*)rois)[vB * P + lane];

        // Sentinel-ized coords: invalid depths -> +INF (auto-fail box tests).
        const float pxs = ok ? px : INFINITY;
        const float pys = ok ? py : INFINITY;
        const int   ipx = __float_as_int(pxs);
        const int   ipy = __float_as_int(pys);

        // Per-half [min,max] over VALID points (xor-butterfly, masks <=16
        // stay within each 32-lane half).
        float xlo = pxs, ylo = pys;
        float xhi = ok ? px : -INFINITY;
        float yhi = ok ? py : -INFINITY;
        #pragma unroll
        for (int m = 16; m >= 1; m >>= 1) {
            xlo = fminf(xlo, __shfl_xor(xlo, m, 64));
            xhi = fmaxf(xhi, __shfl_xor(xhi, m, 64));
            ylo = fminf(ylo, __shfl_xor(ylo, m, 64));
            yhi = fmaxf(yhi, __shfl_xor(yhi, m, 64));
        }
        const float AxL = __int_as_float(__builtin_amdgcn_readlane(__float_as_int(xlo), 0));
        const float AxH = __int_as_float(__builtin_amdgcn_readlane(__float_as_int(xhi), 0));
        const float AyL = __int_as_float(__builtin_amdgcn_readlane(__float_as_int(ylo), 0));
        const float AyH = __int_as_float(__builtin_amdgcn_readlane(__float_as_int(yhi), 0));
        const float BxL = __int_as_float(__builtin_amdgcn_readlane(__float_as_int(xlo), 32));
        const float BxH = __int_as_float(__builtin_amdgcn_readlane(__float_as_int(xhi), 32));
        const float ByL = __int_as_float(__builtin_amdgcn_readlane(__float_as_int(ylo), 32));
        const float ByH = __int_as_float(__builtin_amdgcn_readlane(__float_as_int(yhi), 32));

        const bool anyA = ((unsigned)bal) != 0u;
        const bool anyB = (bal >> 32) != 0ull;

        // ---- pair A ----
        {
            const bool inside = (AxL > ra.x) && (AxH < ra.z) && (AyL > ra.y) && (AyH < ra.w);
            const bool disj   = !(AxH > ra.x) || !(AxL < ra.z) || !(AyH > ra.y) || !(AyL < ra.w);
            bool hit = anyA && inside;
            const bool ambig = anyA && !inside && !disj;
            if (__ballot(ambig) != 0ull) {
                bool h = false;
                #pragma unroll
                for (int q = 0; q < 32; ++q) {
                    const float xd = __int_as_float(__builtin_amdgcn_readlane(ipx, q));
                    const float yd = __int_as_float(__builtin_amdgcn_readlane(ipy, q));
                    h = h || ((xd > ra.x) && (xd < ra.z) && (yd > ra.y) && (yd < ra.w));
                }
                hit = h;   // exact for every lane (sentinels kill invalid depths)
            }
            cA = hit ? 1.0f : 0.0f;
        }
        // ---- pair B ----
        {
            const bool inside = (BxL > rb.x) && (BxH < rb.z) && (ByL > rb.y) && (ByH < rb.w);
            const bool disj   = !(BxH > rb.x) || !(BxL < rb.z) || !(ByH > rb.y) || !(ByL < rb.w);
            bool hit = anyB && inside;
            const bool ambig = anyB && !inside && !disj;
            if (__ballot(ambig) != 0ull) {
                bool h = false;
                #pragma unroll
                for (int q = 0; q < 32; ++q) {
                    const float xd = __int_as_float(__builtin_amdgcn_readlane(ipx, q + 32));
                    const float yd = __int_as_float(__builtin_amdgcn_readlane(ipy, q + 32));
                    h = h || ((xd > rb.x) && (xd < rb.z) && (yd > rb.y) && (yd < rb.w));
                }
                hit = h;
            }
            cB = hit ? 1.0f : 0.0f;
        }
    }

    out_corr[(size_t)pA * P + lane] = cA;
    out_corr[(size_t)pB * P + lane] = cB;
}

extern "C" void kernel_launch(void* const* d_in, const int* in_sizes, int n_in,
                              void* d_out, int out_size, void* d_ws, size_t ws_size,
                              hipStream_t stream) {
    const float* points = (const float*)d_in[0];   // 20000*3
    const float* trans  = (const float*)d_in[1];   // 6*6*4*4
    const float* rois   = (const float*)d_in[2];   // 6*64*4

    float* out      = (float*)d_out;
    float* out_xy   = out;                                   // N*V*ND*2
    float* out_mask = out + (size_t)N * V * ND * 2;          // N*V*ND
    float* out_corr = out_mask + (size_t)N * V * ND;         // N*V*P

    const int waves  = (N * V) / 2;      // 60000 waves, 2 pairs each
    const int blocks = (waves + 3) / 4;  // 4 waves / 256-thread block
    box_corr<<<blocks, 256, 0, stream>>>(points, trans, rois, out_xy, out_mask, out_corr);
}